// Round 1
// baseline (484.420 us; speedup 1.0000x reference)
//
#include <hip/hip_runtime.h>
#include <hip/hip_bf16.h>
#include <stdint.h>

// ExpanderLinear: y[t,o] = sum_i x[t,i] * (w[o,i]*mask[o,i]) + bias[o]
// M=8192 tokens, K=4096 indim, N=4096 outdim. f32 in/out, bf16 MFMA compute.

typedef __attribute__((ext_vector_type(4))) float          f32x4;
typedef __attribute__((ext_vector_type(4))) int            i32x4;
typedef __attribute__((ext_vector_type(4))) unsigned short u16x4;
typedef __attribute__((ext_vector_type(8))) __bf16         bf16x8;

static constexpr int M = 8192;
static constexpr int N = 4096;
static constexpr int K = 4096;

#define BM 128
#define BN 128
#define BK 64

#define GLOBAL_AS(p) ((const __attribute__((address_space(1))) void*)(p))
#define LDS_AS(p)    ((__attribute__((address_space(3))) void*)(p))

// f32 -> bf16 round-to-nearest-even (inputs are finite; no NaN path needed)
__device__ __forceinline__ unsigned short f2bf(float f) {
    unsigned int u = __float_as_uint(f);
    u = (u + 0x7fffu + ((u >> 16) & 1u)) >> 16;
    return (unsigned short)u;
}

// ---- prep 1: x f32 -> bf16 (vectorized, 16B/lane read, 8B/lane write) ----
__global__ void cvt_x_kernel(const float* __restrict__ x,
                             unsigned short* __restrict__ out) {
    int i = blockIdx.x * blockDim.x + threadIdx.x;  // quad index
    f32x4 v = ((const f32x4*)x)[i];
    u16x4 r;
    r.x = f2bf(v.x); r.y = f2bf(v.y); r.z = f2bf(v.z); r.w = f2bf(v.w);
    ((u16x4*)out)[i] = r;
}

// ---- prep 2: (w * mask) f32 -> bf16, fused ----
__global__ void cvt_wm_kernel(const float* __restrict__ w,
                              const int* __restrict__ mask,
                              unsigned short* __restrict__ out) {
    int i = blockIdx.x * blockDim.x + threadIdx.x;
    f32x4 v = ((const f32x4*)w)[i];
    i32x4 m = ((const i32x4*)mask)[i];
    u16x4 r;
    r.x = m.x ? f2bf(v.x) : (unsigned short)0;
    r.y = m.y ? f2bf(v.y) : (unsigned short)0;
    r.z = m.z ? f2bf(v.z) : (unsigned short)0;
    r.w = m.w ? f2bf(v.w) : (unsigned short)0;
    ((u16x4*)out)[i] = r;
}

// ---- main GEMM: C[M][N] = A[M][K] * B[N][K]^T + bias, bf16 MFMA ----
// m97 structure: 128x128 tile, BK=64, 4 waves (2x2), 4x4 frags of 16x16x32,
// global_load_lds width=16 staging (linear LDS), 2-barrier K-loop.
__global__ void __launch_bounds__(256)
gemm_bf16_bt(const unsigned short* __restrict__ A,   // [M][K] bf16 bits
             const unsigned short* __restrict__ B,   // [N][K] bf16 bits
             const float* __restrict__ bias,         // [N]
             float* __restrict__ C) {                // [M][N] f32
    __shared__ unsigned short As[BM * BK];  // 16 KiB, linear row-major [128][64]
    __shared__ unsigned short Bs[BN * BK];  // 16 KiB

    const int tid  = threadIdx.x;
    const int lane = tid & 63;
    const int wave = tid >> 6;

    // XCD-aware bijective swizzle: nwg = 64*32 = 2048, divisible by 8.
    const int nwg = (M / BM) * (N / BN);
    const int cpx = nwg >> 3;
    const int bid = blockIdx.x;
    const int swz = (bid & 7) * cpx + (bid >> 3);
    const int ntn = N / BN;
    const int brow = (swz / ntn) * BM;
    const int bcol = (swz % ntn) * BN;

    // wave -> 64x64 output quadrant
    const int wr = (wave >> 1) * 64;
    const int wc = (wave & 1) * 64;
    // MFMA fragment lane decomposition
    const int fr = lane & 15;   // row (A) / col (B) within 16x16 fragment
    const int fq = lane >> 4;   // k-subgroup 0..3 (8 bf16 each)

    // staging decomposition: wave-inst q covers 1024B = 8 rows x 64 cols bf16;
    // lane covers row q*8 + lane/8, k-offset (lane%8)*8 (16B load).
    const int srow = lane >> 3;
    const int scol = (lane & 7) * 8;

    const unsigned short* aptr = A + (size_t)brow * K;
    const unsigned short* bptr = B + (size_t)bcol * K;

    f32x4 acc[4][4];
#pragma unroll
    for (int m = 0; m < 4; ++m)
#pragma unroll
        for (int n = 0; n < 4; ++n)
            acc[m][n] = (f32x4)(0.0f);

    for (int k0 = 0; k0 < K; k0 += BK) {
        __syncthreads();  // previous tile's ds_reads done before overwrite
#pragma unroll
        for (int c = 0; c < 4; ++c) {
            const int q   = c * 4 + wave;       // 0..15, wave-uniform
            const int row = q * 8 + srow;
            __builtin_amdgcn_global_load_lds(
                GLOBAL_AS(aptr + (size_t)row * K + k0 + scol),
                LDS_AS(As + q * 512), 16, 0, 0);
            __builtin_amdgcn_global_load_lds(
                GLOBAL_AS(bptr + (size_t)row * K + k0 + scol),
                LDS_AS(Bs + q * 512), 16, 0, 0);
        }
        __syncthreads();  // compiler drains vmcnt(0) before s_barrier

#pragma unroll
        for (int kk = 0; kk < BK / 32; ++kk) {
            bf16x8 af[4], bfv[4];
#pragma unroll
            for (int m = 0; m < 4; ++m)
                af[m] = *(const bf16x8*)(As + (wr + m * 16 + fr) * BK + kk * 32 + fq * 8);
#pragma unroll
            for (int n = 0; n < 4; ++n)
                bfv[n] = *(const bf16x8*)(Bs + (wc + n * 16 + fr) * BK + kk * 32 + fq * 8);
#pragma unroll
            for (int m = 0; m < 4; ++m)
#pragma unroll
                for (int n = 0; n < 4; ++n)
                    acc[m][n] = __builtin_amdgcn_mfma_f32_16x16x32_bf16(
                        af[m], bfv[n], acc[m][n], 0, 0, 0);
        }
    }

    // epilogue: C/D layout col=lane&15, row=(lane>>4)*4+reg  [m89/m91 verified]
    float bv[4];
#pragma unroll
    for (int n = 0; n < 4; ++n) bv[n] = bias[bcol + wc + n * 16 + fr];

#pragma unroll
    for (int m = 0; m < 4; ++m) {
#pragma unroll
        for (int j = 0; j < 4; ++j) {
            const int row = brow + wr + m * 16 + fq * 4 + j;
            float* crow = C + (size_t)row * N + bcol + wc + fr;
#pragma unroll
            for (int n = 0; n < 4; ++n)
                crow[n * 16] = acc[m][n][j] + bv[n];
        }
    }
}

// ---- fallback (only if ws_size too small): f32 vector GEMM, mask on the fly ----
__global__ void fallback_gemm(const float* __restrict__ x,
                              const float* __restrict__ w,
                              const int* __restrict__ mask,
                              const float* __restrict__ bias,
                              float* __restrict__ C) {
    const int tid = threadIdx.x;
    const int tx = tid & 15, ty = tid >> 4;
    const int brow = blockIdx.y * 64, bcol = blockIdx.x * 64;
    __shared__ float As[64][17];
    __shared__ float Ws[64][17];
    float acc[4][4] = {};
    for (int k0 = 0; k0 < K; k0 += 16) {
        __syncthreads();
        for (int i = tid; i < 64 * 16; i += 256) {
            int r = i >> 4, c = i & 15;
            As[r][c] = x[(size_t)(brow + r) * K + k0 + c];
            float wv = w[(size_t)(bcol + r) * K + k0 + c];
            Ws[r][c] = mask[(size_t)(bcol + r) * K + k0 + c] ? wv : 0.0f;
        }
        __syncthreads();
        for (int kk = 0; kk < 16; ++kk) {
            float a[4], b[4];
#pragma unroll
            for (int i = 0; i < 4; ++i) a[i] = As[ty * 4 + i][kk];
#pragma unroll
            for (int i = 0; i < 4; ++i) b[i] = Ws[tx * 4 + i][kk];
#pragma unroll
            for (int i = 0; i < 4; ++i)
#pragma unroll
                for (int j = 0; j < 4; ++j) acc[i][j] += a[i] * b[j];
        }
    }
    for (int i = 0; i < 4; ++i)
        for (int j = 0; j < 4; ++j) {
            int row = brow + ty * 4 + i, col = bcol + tx * 4 + j;
            C[(size_t)row * N + col] = acc[i][j] + bias[col];
        }
}

extern "C" void kernel_launch(void* const* d_in, const int* in_sizes, int n_in,
                              void* d_out, int out_size, void* d_ws, size_t ws_size,
                              hipStream_t stream) {
    const float* x    = (const float*)d_in[0];
    const float* w    = (const float*)d_in[1];
    const float* bias = (const float*)d_in[2];
    const int*   mask = (const int*)d_in[3];
    float* out = (float*)d_out;

    const size_t need = ((size_t)M * K + (size_t)N * K) * sizeof(unsigned short);
    if (ws_size >= need) {
        unsigned short* xb = (unsigned short*)d_ws;           // [M][K] bf16
        unsigned short* wb = xb + (size_t)M * K;              // [N][K] bf16
        cvt_x_kernel<<<(M * K / 4) / 256, 256, 0, stream>>>(x, xb);
        cvt_wm_kernel<<<(N * K / 4) / 256, 256, 0, stream>>>(w, mask, wb);
        gemm_bf16_bt<<<(M / BM) * (N / BN), 256, 0, stream>>>(xb, wb, bias, out);
    } else {
        dim3 g(N / 64, M / 64);
        fallback_gemm<<<g, 256, 0, stream>>>(x, w, mask, bias, out);
    }
}

// Round 2
// 297.906 us; speedup vs baseline: 1.6261x; 1.6261x over previous
//
#include <hip/hip_runtime.h>
#include <hip/hip_bf16.h>
#include <stdint.h>

// ExpanderLinear: y[t,o] = sum_i x[t,i] * (w[o,i]*mask[o,i]) + bias[o]
// M=8192, K=4096, N=4096. f32 in/out, bf16 MFMA compute.
// GEMM: 256x256 tile, 8 waves, ring-4 half-K LDS units, counted-vmcnt phases
// (T1 XCD swizzle + T2 LDS swizzle + T3/T4 phases + T5 setprio).

typedef __attribute__((ext_vector_type(4))) float          f32x4;
typedef __attribute__((ext_vector_type(4))) int            i32x4;
typedef __attribute__((ext_vector_type(4))) unsigned short u16x4;
typedef __attribute__((ext_vector_type(8))) __bf16         bf16x8;

static constexpr int M = 8192;
static constexpr int N = 4096;
static constexpr int K = 4096;

#define BM 256
#define BN 256
#define NT (K / 64)

#define GLOBAL_AS(p) ((const __attribute__((address_space(1))) void*)(p))
#define LDS_AS(p)    ((__attribute__((address_space(3))) void*)(p))

__device__ __forceinline__ unsigned short f2bf(float f) {
    unsigned int u = __float_as_uint(f);
    u = (u + 0x7fffu + ((u >> 16) & 1u)) >> 16;
    return (unsigned short)u;
}

// ---- prep 1: x f32 -> bf16 ----
__global__ void cvt_x_kernel(const float* __restrict__ x,
                             unsigned short* __restrict__ out) {
    int i = blockIdx.x * blockDim.x + threadIdx.x;
    f32x4 v = ((const f32x4*)x)[i];
    u16x4 r;
    r.x = f2bf(v.x); r.y = f2bf(v.y); r.z = f2bf(v.z); r.w = f2bf(v.w);
    ((u16x4*)out)[i] = r;
}

// ---- prep 2: (w * mask) f32 -> bf16, fused ----
__global__ void cvt_wm_kernel(const float* __restrict__ w,
                              const int* __restrict__ mask,
                              unsigned short* __restrict__ out) {
    int i = blockIdx.x * blockDim.x + threadIdx.x;
    f32x4 v = ((const f32x4*)w)[i];
    i32x4 m = ((const i32x4*)mask)[i];
    u16x4 r;
    r.x = m.x ? f2bf(v.x) : (unsigned short)0;
    r.y = m.y ? f2bf(v.y) : (unsigned short)0;
    r.z = m.z ? f2bf(v.z) : (unsigned short)0;
    r.w = m.w ? f2bf(v.w) : (unsigned short)0;
    ((u16x4*)out)[i] = r;
}

// ---- main GEMM ----
// LDS: A-ring = 4 units of [256 rows][32 bf16] (16KB each), B-ring same.
// Unit for (tile t, k-half h) lives in slot (2t+h)&3.
// Swizzle (within 128B row-pair): s3 = (((row&1)<<2)|slot16) ^ ((row>>1)&7).
// Writes stay linear (global_load_lds); the global SOURCE is pre-swizzled.
__global__ void __launch_bounds__(512, 2)
gemm8_bf16(const unsigned short* __restrict__ A,   // [M][K] bf16 bits
           const unsigned short* __restrict__ B,   // [N][K] bf16 bits
           const float* __restrict__ bias,         // [N]
           float* __restrict__ C) {                // [M][N] f32
    extern __shared__ unsigned short lds[];
    unsigned short* __restrict__ Au = lds;            // 4 * 8192 elems
    unsigned short* __restrict__ Bu = lds + 32768;    // 4 * 8192 elems

    const int tid  = threadIdx.x;
    const int lane = tid & 63;
    const int wave = tid >> 6;

    // T1: XCD-aware bijective swizzle (nwg = 512, % 8 == 0)
    const int bid = blockIdx.x;
    const int cpx = (M / BM) * (N / BN) / 8;   // 64
    const int swz = (bid & 7) * cpx + (bid >> 3);
    const int ntn = N / BN;                    // 16
    const int brow = (swz / ntn) * BM;
    const int bcol = (swz % ntn) * BN;

    const int wrow = (wave >> 2) * 128;        // wave output rows
    const int wcol = (wave & 3) * 64;          // wave output cols
    const int fr = lane & 15;                  // fragment row/col
    const int fq = lane >> 4;                  // k-subgroup

    // read-side swizzle: per-lane constant
    const int s3r   = (((fr & 1) << 2) | fq) ^ (fr >> 1);
    const int abase = ((wrow >> 1) + (fr >> 1)) * 128 + s3r * 16;  // + m*1024
    const int bbase = ((wcol >> 1) + (fr >> 1)) * 128 + s3r * 16;  // + n*1024

    // write-side: lane's linear LDS slot maps to this logical (row, col)
    const int l8 = lane & 7, lh = lane >> 3;
    const int s3w    = l8 ^ lh;
    const int wrow_l = 2 * lh + (s3w >> 2);    // row within 16-row call block
    const int wcol_l = (s3w & 3) * 8;          // bf16 col within 32-col unit

    const unsigned short* __restrict__ Ag = A + (size_t)brow * K;
    const unsigned short* __restrict__ Bg = B + (size_t)bcol * K;

    f32x4 acc[8][4];
#pragma unroll
    for (int m = 0; m < 8; ++m)
#pragma unroll
        for (int n = 0; n < 4; ++n) acc[m][n] = (f32x4)(0.0f);

    bf16x8 af[8], bfv[2];

#define STG1(dst, src) __builtin_amdgcn_global_load_lds(GLOBAL_AS(src), LDS_AS(dst), 16, 0, 0)
#define STGA(slot, kcol) do {                                                   \
    STG1(Au + (slot) * 8192 + wave * 512,                                       \
         Ag + (size_t)(wave * 16 + wrow_l) * K + (kcol) + wcol_l);              \
    STG1(Au + (slot) * 8192 + (wave + 8) * 512,                                 \
         Ag + (size_t)((wave + 8) * 16 + wrow_l) * K + (kcol) + wcol_l);        \
  } while (0)
#define STGB(slot, kcol) do {                                                   \
    STG1(Bu + (slot) * 8192 + wave * 512,                                       \
         Bg + (size_t)(wave * 16 + wrow_l) * K + (kcol) + wcol_l);              \
    STG1(Bu + (slot) * 8192 + (wave + 8) * 512,                                 \
         Bg + (size_t)((wave + 8) * 16 + wrow_l) * K + (kcol) + wcol_l);        \
  } while (0)
#define LDA(unit) do {                                                          \
    const char* ub_ = (const char*)(Au + (unit) * 8192);                        \
    _Pragma("unroll")                                                           \
    for (int m = 0; m < 8; ++m)                                                 \
        af[m] = *(const bf16x8*)(ub_ + abase + m * 1024);                       \
  } while (0)
#define LDB(unit, np) do {                                                      \
    const char* vb_ = (const char*)(Bu + (unit) * 8192);                        \
    bfv[0] = *(const bf16x8*)(vb_ + bbase + (np) * 2048);                       \
    bfv[1] = *(const bf16x8*)(vb_ + bbase + (np) * 2048 + 1024);                \
  } while (0)
#define MM(np) do {                                                             \
    __builtin_amdgcn_s_setprio(1);                                              \
    _Pragma("unroll")                                                           \
    for (int m = 0; m < 8; ++m) {                                               \
      acc[m][(np) * 2] = __builtin_amdgcn_mfma_f32_16x16x32_bf16(               \
          af[m], bfv[0], acc[m][(np) * 2], 0, 0, 0);                            \
      acc[m][(np) * 2 + 1] = __builtin_amdgcn_mfma_f32_16x16x32_bf16(           \
          af[m], bfv[1], acc[m][(np) * 2 + 1], 0, 0, 0);                        \
    }                                                                           \
    __builtin_amdgcn_s_setprio(0);                                              \
  } while (0)
#define BAR   __builtin_amdgcn_s_barrier()
#define WLGKM asm volatile("s_waitcnt lgkmcnt(0)" ::: "memory")
#define WVM4  asm volatile("s_waitcnt vmcnt(4)" ::: "memory")
#define WVM0  asm volatile("s_waitcnt vmcnt(0)" ::: "memory")

    // prologue: stage tile 0 (kh0->slot0, kh1->slot1); keep kh1 in flight
    STGA(0, 0); STGB(0, 0); STGA(1, 32); STGB(1, 32);
    WVM4;
    BAR;

    for (int t = 0; t < NT - 1; ++t) {
        const int u0 = (2 * t) & 3;
        const int u1 = (2 * t + 1) & 3;
        const int s0 = (2 * t + 2) & 3;   // stage slots for tile t+1
        const int s1 = (2 * t + 3) & 3;
        const int kn = (t + 1) * 64;
        // P1: n-pair 0 x kh0
        LDA(u0); LDB(u0, 0); STGA(s0, kn);
        BAR; WLGKM; MM(0); BAR;
        // P2: n-pair 1 x kh0; retire this tile's kh1 units
        LDB(u0, 1); STGB(s0, kn);
        BAR; WLGKM; MM(1); WVM4; BAR;
        // P3: n-pair 0 x kh1
        LDA(u1); LDB(u1, 0); STGA(s1, kn + 32);
        BAR; WLGKM; MM(0); BAR;
        // P4: n-pair 1 x kh1; retire next tile's kh0 units
        LDB(u1, 1); STGB(s1, kn + 32);
        BAR; WLGKM; MM(1); WVM4; BAR;
    }
    {   // last tile: no staging; drain
        const int u0 = (2 * (NT - 1)) & 3;
        const int u1 = (2 * (NT - 1) + 1) & 3;
        LDA(u0); LDB(u0, 0);
        BAR; WLGKM; MM(0); BAR;
        LDB(u0, 1);
        BAR; WLGKM; MM(1); WVM0; BAR;
        LDA(u1); LDB(u1, 0);
        BAR; WLGKM; MM(0); BAR;
        LDB(u1, 1);
        BAR; WLGKM; MM(1);
    }

    // epilogue: C/D layout col=lane&15, row=(lane>>4)*4+reg [m89/m91]
    float bv[4];
#pragma unroll
    for (int n = 0; n < 4; ++n) bv[n] = bias[bcol + wcol + n * 16 + fr];
#pragma unroll
    for (int m = 0; m < 8; ++m) {
#pragma unroll
        for (int j = 0; j < 4; ++j) {
            const int row = brow + wrow + m * 16 + fq * 4 + j;
            float* crow = C + (size_t)row * N + bcol + wcol + fr;
#pragma unroll
            for (int n = 0; n < 4; ++n) crow[n * 16] = acc[m][n][j] + bv[n];
        }
    }
#undef STG1
#undef STGA
#undef STGB
#undef LDA
#undef LDB
#undef MM
#undef BAR
#undef WLGKM
#undef WVM4
#undef WVM0
}

// ---- fallback (only if ws too small): f32 vector GEMM ----
__global__ void fallback_gemm(const float* __restrict__ x,
                              const float* __restrict__ w,
                              const int* __restrict__ mask,
                              const float* __restrict__ bias,
                              float* __restrict__ C) {
    const int tid = threadIdx.x;
    const int tx = tid & 15, ty = tid >> 4;
    const int brow = blockIdx.y * 64, bcol = blockIdx.x * 64;
    __shared__ float As[64][17];
    __shared__ float Ws[64][17];
    float acc[4][4] = {};
    for (int k0 = 0; k0 < K; k0 += 16) {
        __syncthreads();
        for (int i = tid; i < 64 * 16; i += 256) {
            int r = i >> 4, c = i & 15;
            As[r][c] = x[(size_t)(brow + r) * K + k0 + c];
            float wv = w[(size_t)(bcol + r) * K + k0 + c];
            Ws[r][c] = mask[(size_t)(bcol + r) * K + k0 + c] ? wv : 0.0f;
        }
        __syncthreads();
        for (int kk = 0; kk < 16; ++kk) {
            float a[4], b[4];
#pragma unroll
            for (int i = 0; i < 4; ++i) a[i] = As[ty * 4 + i][kk];
#pragma unroll
            for (int i = 0; i < 4; ++i) b[i] = Ws[tx * 4 + i][kk];
#pragma unroll
            for (int i = 0; i < 4; ++i)
#pragma unroll
                for (int j = 0; j < 4; ++j) acc[i][j] += a[i] * b[j];
        }
    }
    for (int i = 0; i < 4; ++i)
        for (int j = 0; j < 4; ++j) {
            int row = brow + ty * 4 + i, col = bcol + tx * 4 + j;
            C[(size_t)row * N + col] = acc[i][j] + bias[col];
        }
}

extern "C" void kernel_launch(void* const* d_in, const int* in_sizes, int n_in,
                              void* d_out, int out_size, void* d_ws, size_t ws_size,
                              hipStream_t stream) {
    const float* x    = (const float*)d_in[0];
    const float* w    = (const float*)d_in[1];
    const float* bias = (const float*)d_in[2];
    const int*   mask = (const int*)d_in[3];
    float* out = (float*)d_out;

    const size_t need = ((size_t)M * K + (size_t)N * K) * sizeof(unsigned short);
    if (ws_size >= need) {
        unsigned short* xb = (unsigned short*)d_ws;           // [M][K] bf16
        unsigned short* wb = xb + (size_t)M * K;              // [N][K] bf16
        (void)hipFuncSetAttribute((const void*)gemm8_bf16,
                                  hipFuncAttributeMaxDynamicSharedMemorySize,
                                  131072);
        cvt_x_kernel<<<(M * K / 4) / 256, 256, 0, stream>>>(x, xb);
        cvt_wm_kernel<<<(N * K / 4) / 256, 256, 0, stream>>>(w, mask, wb);
        gemm8_bf16<<<(M / BM) * (N / BN), 512, 131072, stream>>>(xb, wb, bias, out);
    } else {
        dim3 g(N / 64, M / 64);
        fallback_gemm<<<g, 256, 0, stream>>>(x, w, mask, bias, out);
    }
}